// Round 8
// baseline (3608.517 us; speedup 1.0000x reference)
//
#include <hip/hip_runtime.h>
#include <hip/hip_bf16.h>
#include <cstdint>
#include <cstddef>

typedef __bf16 bf16;
typedef bf16 bf16x8 __attribute__((ext_vector_type(8)));
typedef bf16 bf16x4 __attribute__((ext_vector_type(4)));
typedef float f32x4 __attribute__((ext_vector_type(4)));
typedef unsigned int u32;

#define GLD_LDS16(gptr, lptr)                                                        \
  __builtin_amdgcn_global_load_lds((const __attribute__((address_space(1))) u32*)(gptr), \
                                   (__attribute__((address_space(3))) u32*)(lptr), 16, 0, 0)

static constexpr int S = 36, D = 768, H = 12, HD = 64, DFF = 1536;
static constexpr int BC = 1536;        // B*C images
static constexpr int M = BC * S;       // 55296 tokens
static constexpr int OUTD = 256;

// ---------------------------------------------------------------- fp32 -> bf16
__global__ __launch_bounds__(256) void f2b_kernel(const float* __restrict__ in,
                                                  bf16* __restrict__ out, int n4) {
  int i = blockIdx.x * 256 + threadIdx.x;
  if (i < n4) {
    float4 f = ((const float4*)in)[i];
    bf16x4 o = {(bf16)f.x, (bf16)f.y, (bf16)f.z, (bf16)f.w};
    ((bf16x4*)out)[i] = o;
  }
}

// ---------------------------------------------------------------- zero / stats finalize
__global__ __launch_bounds__(256) void zerok(float* __restrict__ p, int n) {
  int i = blockIdx.x * 256 + threadIdx.x;
  if (i < n) p[i] = 0.f;
}
__global__ __launch_bounds__(256) void stats_fin(const float* __restrict__ sacc,
                                                 float* __restrict__ stats, int n) {
  int i = blockIdx.x * 256 + threadIdx.x;
  if (i < n) {
    float sm = sacc[(size_t)i * 2] * (1.f / 768.f);
    float sq = sacc[(size_t)i * 2 + 1] * (1.f / 768.f);
    float var = sq - sm * sm;
    stats[(size_t)i * 2] = sm;
    stats[(size_t)i * 2 + 1] = rsqrtf(var + 1e-5f);
  }
}

// ---------------------------------------------------------------- Wqk = Wq^T Wk, vk = Wk^T bq
__global__ __launch_bounds__(64) void qk_prep(const float* __restrict__ Wq,
                                              const float* __restrict__ Wk,
                                              const float* __restrict__ bq,
                                              bf16* __restrict__ wb,
                                              float* __restrict__ vkout) {
  int lh = blockIdx.x;                 // 0..47 = l*12+h
  int e = threadIdx.x;                 // 0..63
  __shared__ float Wqs[64][64];        // [f][d]
  __shared__ float Wks[64][64];        // [f][e]
  const float* wqp = Wq + (size_t)lh * 4096;
  const float* wkp = Wk + (size_t)lh * 4096;
  for (int i = e; i < 4096; i += 64) {
    Wqs[i >> 6][i & 63] = wqp[i];
    Wks[i >> 6][i & 63] = wkp[i];
  }
  __syncthreads();
  float ks[64];
#pragma unroll
  for (int f = 0; f < 64; ++f) ks[f] = Wks[f][e];
  for (int d0 = 0; d0 < 64; d0 += 4) {
    float a0 = 0.f, a1 = 0.f, a2 = 0.f, a3 = 0.f;
#pragma unroll
    for (int f = 0; f < 64; ++f) {
      float4 wq4 = *(const float4*)&Wqs[f][d0];   // broadcast read
      a0 += wq4.x * ks[f]; a1 += wq4.y * ks[f];
      a2 += wq4.z * ks[f]; a3 += wq4.w * ks[f];
    }
    bf16x4 o = {(bf16)a0, (bf16)a1, (bf16)a2, (bf16)a3};
    *(bf16x4*)&wb[(size_t)lh * 4096 + e * 64 + d0] = o;
  }
  const float* bqp = bq + lh * 64;
  float acc = 0.f;
#pragma unroll
  for (int f = 0; f < 64; ++f) acc += ks[f] * bqp[f];
  vkout[lh * 64 + e] = acc;
}

// ---------------------------------------------------------------- patch embed
__global__ __launch_bounds__(256) void patch_embed(const float* __restrict__ batch,
                                                   const float* __restrict__ Wp,
                                                   const float* __restrict__ bp,
                                                   const float* __restrict__ pos,
                                                   float* __restrict__ z) {
  int bc = blockIdx.x, tid = threadIdx.x;
  __shared__ float p[36][40];          // [token][pixel], padded row
  for (int i = tid; i < 1296; i += 256) {
    float f = batch[(size_t)bc * 1296 + i];
    int row = i / 36, col = i - row * 36;
    p[(row / 6) * 6 + col / 6][(row % 6) * 6 + (col % 6)] = f;
  }
  __syncthreads();
  for (int c0 = 0; c0 < 768; c0 += 256) {
    int d = c0 + tid;
    float wr[36];
    const float4* wp4 = (const float4*)(Wp + (size_t)d * 36);   // 144B rows, 16B aligned
#pragma unroll
    for (int q = 0; q < 9; ++q) {
      float4 f = wp4[q];
      wr[q * 4] = f.x; wr[q * 4 + 1] = f.y; wr[q * 4 + 2] = f.z; wr[q * 4 + 3] = f.w;
    }
    float gb = bp[d];
    for (int s = 0; s < 36; ++s) {
      float acc = 0.f;
#pragma unroll
      for (int k = 0; k < 36; ++k) acc += p[s][k] * wr[k];
      z[((size_t)bc * 36 + s) * 768 + d] = acc + gb + pos[s * 768 + d];
    }
  }
}

// ---------------------------------------------------------------- LN stats (mean, rstd) per row
__global__ __launch_bounds__(256) void ln_stats(const float* __restrict__ zin,
                                                float* __restrict__ stats) {
  int row = blockIdx.x * 4 + (threadIdx.x >> 6);
  int lane = threadIdx.x & 63;
  const float* zr = zin + (size_t)row * D;
  float x[12];
#pragma unroll
  for (int i = 0; i < 12; ++i) x[i] = zr[i * 64 + lane];
  float s = 0.f;
#pragma unroll
  for (int i = 0; i < 12; ++i) s += x[i];
#pragma unroll
  for (int off = 32; off >= 1; off >>= 1) s += __shfl_xor(s, off, 64);
  float m = s * (1.f / 768.f);
  float v = 0.f;
#pragma unroll
  for (int i = 0; i < 12; ++i) { float dd = x[i] - m; v += dd * dd; }
#pragma unroll
  for (int off = 32; off >= 1; off >>= 1) v += __shfl_xor(v, off, 64);
  v *= (1.f / 768.f);
  if (lane == 0) {
    stats[(size_t)row * 2] = m;
    stats[(size_t)row * 2 + 1] = rsqrtf(v + 1e-5f);
  }
}

// ---------------------------------------------------------------- LN in-place (fp32) + bf16 dup
// row-chunk launch; zb receives a bf16 mirror so GEMM1 (256-tile, gld_lds) reads bf16 A.
__global__ __launch_bounds__(256) void ln_inplace(float* __restrict__ z,
                                                  const float* __restrict__ g,
                                                  const float* __restrict__ bt,
                                                  bf16* __restrict__ zb) {
  int row = blockIdx.x * 4 + (threadIdx.x >> 6);
  int lane = threadIdx.x & 63;
  float* zr = z + (size_t)row * D;
  float x[12];
#pragma unroll
  for (int i = 0; i < 12; ++i) x[i] = zr[i * 64 + lane];
  float s = 0.f;
#pragma unroll
  for (int i = 0; i < 12; ++i) s += x[i];
#pragma unroll
  for (int off = 32; off >= 1; off >>= 1) s += __shfl_xor(s, off, 64);
  float m = s * (1.f / 768.f);
  float v = 0.f;
#pragma unroll
  for (int i = 0; i < 12; ++i) { float dd = x[i] - m; v += dd * dd; }
#pragma unroll
  for (int off = 32; off >= 1; off >>= 1) v += __shfl_xor(v, off, 64);
  v *= (1.f / 768.f);
  float rstd = rsqrtf(v + 1e-5f);
  bf16* zbr = zb ? zb + (size_t)row * D : nullptr;
#pragma unroll
  for (int i = 0; i < 12; ++i) {
    int d = i * 64 + lane;
    float o = (x[i] - m) * rstd * g[d] + bt[d];
    zr[d] = o;
    if (zbr) zbr[d] = (bf16)o;
  }
}

// ---------------------------------------------------------------- fused attention (G-trick)
__global__ __launch_bounds__(64) void attn_kernel(const float* __restrict__ zg,
                                                  const float* __restrict__ stats,
                                                  const float* __restrict__ g1,
                                                  const float* __restrict__ b1_,
                                                  const bf16* __restrict__ Wqk,
                                                  const bf16* __restrict__ Wv,
                                                  const float* __restrict__ vk,
                                                  const float* __restrict__ bv,
                                                  float* __restrict__ z) {
  int head = blockIdx.x;
  int bc = blockIdx.y;
  __shared__ __align__(16) bf16 gb[48 * 72];   // G, later P
  __shared__ __align__(16) bf16 vt[64 * 72];   // vt[e][t]
  int lane = threadIdx.x;
  int lr = lane & 15, quad = lane >> 4;

#pragma unroll
  for (int t0 = 0; t0 < 16; ++t0) vt[lane * 72 + 48 + t0] = (bf16)0.f;

  const float* zsrc = zg + ((size_t)bc * S) * D + head * HD;
  const float* st = stats + (size_t)bc * S * 2;

  float gv[2][8], bvv[2][8];
#pragma unroll
  for (int kt = 0; kt < 2; ++kt) {
    int c0 = head * HD + kt * 32 + quad * 8;
    float4 ga = *(const float4*)(g1 + c0);
    float4 gb2 = *(const float4*)(g1 + c0 + 4);
    float4 ba = *(const float4*)(b1_ + c0);
    float4 bb2 = *(const float4*)(b1_ + c0 + 4);
    gv[kt][0] = ga.x; gv[kt][1] = ga.y; gv[kt][2] = ga.z; gv[kt][3] = ga.w;
    gv[kt][4] = gb2.x; gv[kt][5] = gb2.y; gv[kt][6] = gb2.z; gv[kt][7] = gb2.w;
    bvv[kt][0] = ba.x; bvv[kt][1] = ba.y; bvv[kt][2] = ba.z; bvv[kt][3] = ba.w;
    bvv[kt][4] = bb2.x; bvv[kt][5] = bb2.y; bvv[kt][6] = bb2.z; bvv[kt][7] = bb2.w;
  }

  bf16x8 hfrag[3][2];
#pragma unroll
  for (int mt = 0; mt < 3; ++mt) {
    int srow = mt * 16 + lr;
    if (srow < 36) {
      float mm = st[srow * 2], rr = st[srow * 2 + 1];
#pragma unroll
      for (int kt = 0; kt < 2; ++kt) {
        int c0 = kt * 32 + quad * 8;
        float4 f0 = *(const float4*)(zsrc + (size_t)srow * D + c0);
        float4 f1 = *(const float4*)(zsrc + (size_t)srow * D + c0 + 4);
        float hv[8] = {f0.x, f0.y, f0.z, f0.w, f1.x, f1.y, f1.z, f1.w};
        bf16x8 o;
#pragma unroll
        for (int j = 0; j < 8; ++j) o[j] = (bf16)((hv[j] - mm) * rr * gv[kt][j] + bvv[kt][j]);
        hfrag[mt][kt] = o;
      }
    } else {
#pragma unroll
      for (int kt = 0; kt < 2; ++kt) {
        bf16x8 o;
#pragma unroll
        for (int j = 0; j < 8; ++j) o[j] = (bf16)0.f;
        hfrag[mt][kt] = o;
      }
    }
  }

  float vkv[2][8];
#pragma unroll
  for (int kt = 0; kt < 2; ++kt) {
    int c0 = head * 64 + kt * 32 + quad * 8;
    float4 va = *(const float4*)(vk + c0);
    float4 vb2 = *(const float4*)(vk + c0 + 4);
    vkv[kt][0] = va.x; vkv[kt][1] = va.y; vkv[kt][2] = va.z; vkv[kt][3] = va.w;
    vkv[kt][4] = vb2.x; vkv[kt][5] = vb2.y; vkv[kt][6] = vb2.z; vkv[kt][7] = vb2.w;
  }
  float tv[3];
#pragma unroll
  for (int mt = 0; mt < 3; ++mt) {
    float sp = 0.f;
#pragma unroll
    for (int kt = 0; kt < 2; ++kt)
#pragma unroll
      for (int j = 0; j < 8; ++j) sp += (float)hfrag[mt][kt][j] * vkv[kt][j];
    sp += __shfl_xor(sp, 16, 64);
    sp += __shfl_xor(sp, 32, 64);
    tv[mt] = sp;
  }

  const bf16* Wm[2] = {Wqk + (size_t)head * 4096, Wv + (size_t)head * 4096};
  const float* bvp = bv + head * 64;
  for (int p = 0; p < 2; ++p) {
    bf16x8 bfr[4][2];
#pragma unroll
    for (int nt = 0; nt < 4; ++nt)
#pragma unroll
      for (int kt = 0; kt < 2; ++kt)
        bfr[nt][kt] = *(const bf16x8*)(Wm[p] + (nt * 16 + lr) * 64 + kt * 32 + quad * 8);
#pragma unroll
    for (int mt = 0; mt < 3; ++mt) {
      f32x4 acc[4] = {};
#pragma unroll
      for (int kt = 0; kt < 2; ++kt)
#pragma unroll
        for (int nt = 0; nt < 4; ++nt)
          acc[nt] = __builtin_amdgcn_mfma_f32_16x16x32_bf16(hfrag[mt][kt], bfr[nt][kt], acc[nt], 0, 0, 0);
#pragma unroll
      for (int nt = 0; nt < 4; ++nt) {
        float bb = (p == 1) ? bvp[nt * 16 + lr] : 0.f;
#pragma unroll
        for (int r = 0; r < 4; ++r) {
          int s2 = mt * 16 + quad * 4 + r;
          int e = nt * 16 + lr;
          float val = acc[nt][r] + bb;
          if (p == 0) gb[s2 * 72 + e] = (bf16)val;
          else vt[e * 72 + s2] = (bf16)val;
        }
      }
    }
  }
  __syncthreads();

  f32x4 sc[3][3];
#pragma unroll
  for (int mt = 0; mt < 3; ++mt)
#pragma unroll
    for (int nt = 0; nt < 3; ++nt) {
      f32x4 a = {};
#pragma unroll
      for (int kt = 0; kt < 2; ++kt) {
        bf16x8 af = *(const bf16x8*)&gb[(mt * 16 + lr) * 72 + kt * 32 + quad * 8];
        a = __builtin_amdgcn_mfma_f32_16x16x32_bf16(af, hfrag[nt][kt], a, 0, 0, 0);
      }
      int t = nt * 16 + lr;
#pragma unroll
      for (int r = 0; r < 4; ++r) {
        float v = (a[r] + tv[nt]) * 0.125f;     // 1/sqrt(64)
        if (t >= 36) v = -1e30f;
        sc[mt][nt][r] = v;
      }
    }
  __syncthreads();

#pragma unroll
  for (int mt = 0; mt < 3; ++mt) {
    float mx[4], sum[4];
#pragma unroll
    for (int r = 0; r < 4; ++r)
      mx[r] = fmaxf(fmaxf(sc[mt][0][r], sc[mt][1][r]), sc[mt][2][r]);
#pragma unroll
    for (int r = 0; r < 4; ++r)
#pragma unroll
      for (int off = 8; off >= 1; off >>= 1) mx[r] = fmaxf(mx[r], __shfl_xor(mx[r], off, 64));
#pragma unroll
    for (int r = 0; r < 4; ++r) sum[r] = 0.f;
#pragma unroll
    for (int nt = 0; nt < 3; ++nt)
#pragma unroll
      for (int r = 0; r < 4; ++r) {
        float e = __expf(sc[mt][nt][r] - mx[r]);
        sc[mt][nt][r] = e;
        sum[r] += e;
      }
#pragma unroll
    for (int r = 0; r < 4; ++r)
#pragma unroll
      for (int off = 8; off >= 1; off >>= 1) sum[r] += __shfl_xor(sum[r], off, 64);
#pragma unroll
    for (int nt = 0; nt < 4; ++nt)
#pragma unroll
      for (int r = 0; r < 4; ++r) {
        int s2 = mt * 16 + quad * 4 + r;
        int t = nt * 16 + lr;
        float pv = (nt < 3) ? sc[mt][nt][r] / sum[r] : 0.f;
        gb[s2 * 72 + t] = (bf16)pv;
      }
  }
  __syncthreads();

#pragma unroll
  for (int mt = 0; mt < 3; ++mt) {
    f32x4 o[4] = {};
#pragma unroll
    for (int kt = 0; kt < 2; ++kt) {
      bf16x8 a = *(const bf16x8*)&gb[(mt * 16 + lr) * 72 + kt * 32 + quad * 8];
#pragma unroll
      for (int nt = 0; nt < 4; ++nt) {
        bf16x8 b = *(const bf16x8*)&vt[(nt * 16 + lr) * 72 + kt * 32 + quad * 8];
        o[nt] = __builtin_amdgcn_mfma_f32_16x16x32_bf16(a, b, o[nt], 0, 0, 0);
      }
    }
#pragma unroll
    for (int nt = 0; nt < 4; ++nt)
#pragma unroll
      for (int r = 0; r < 4; ++r) {
        int s2 = mt * 16 + quad * 4 + r;
        if (s2 < 36) {
          int e = nt * 16 + lr;
          size_t idx = ((size_t)bc * S + s2) * D + head * HD + e;
          z[idx] += o[nt][r];
        }
      }
  }
}

// ---------------------------------------------------------------- 256x256 GEMM, counted-vmcnt dbuf
// R8: 8 waves (2Mx4N), per-wave 128x64 out, BK=32, LDS = 2 slots x (A 16K + B 16K) = 64 KB
// static. Schedule per K-tile t: compute(slot t&1) -> sched_barrier+raw s_barrier (reads
// done) -> stage tile t+2 into slot t&1 -> s_waitcnt vmcnt(4 if staged else 0) (retires the
// OLDEST 4 loads = tile t+1's; t+2's stay in flight) -> raw s_barrier -> next tile.
// Loads thus span barriers (T3/T4); no vmcnt(0) drain in steady state.
// FIFO audit: at each wait, outstanding = t+1(<=4, oldest) + t+2(4); vmcnt(4) => t+1 landed.
// MODE 0: bf16 relu(.+bias); MODE 1: f32 .+bias+res; MODE 4: MODE1 + row sum/sumsq atomics.
template <int N, int K, int MODE>
__global__ __launch_bounds__(512) void gemm256(const bf16* __restrict__ A,
                                               const bf16* __restrict__ Bw,
                                               const float* __restrict__ bias,
                                               const float* __restrict__ res,
                                               void* __restrict__ outp,
                                               float* __restrict__ sacc) {
  constexpr int BK = 32;
  constexpr int T = K / BK;
  __shared__ __align__(16) bf16 As[2][256 * BK];
  __shared__ __align__(16) bf16 Bs[2][256 * BK];
  int tid = threadIdx.x;
  int bn = blockIdx.x, bm = blockIdx.y;
  // XCD-aware bijective swizzle (same scheme as the 128-tile kernel, R7-verified)
  if ((gridDim.y & 7) == 0) {
    int gx = gridDim.x, gy = gridDim.y;
    int h = bm * gx + bn;
    int x = h & 7, k = h >> 3;
    int gpc = gy >> 3;
    bm = x * gpc + k / gx;
    bn = k - (k / gx) * gx;
  }
  const bf16* Ab = A + (size_t)bm * 256 * K;
  const bf16* Bb = Bw + (size_t)bn * 256 * K;
  int lane = tid & 63, wave = tid >> 6;
  int wm = wave >> 2, wn = wave & 3;           // 2 x 4 wave grid
  int lr = lane & 15, quad = lane >> 4;

  auto stage = [&](int slot, int t) {
    int k0 = t * BK;
#pragma unroll
    for (int r = 0; r < 2; ++r) {
      int u = r * 512 + tid;                   // 16B units; A-tile = 1024 units
      int row = u >> 2, col = (u & 3) * 8;     // 4 units per 64B row
      GLD_LDS16(Ab + (size_t)row * K + k0 + col, &As[slot][u * 8]);
    }
#pragma unroll
    for (int r = 0; r < 2; ++r) {
      int u = r * 512 + tid;
      int row = u >> 2, col = (u & 3) * 8;
      GLD_LDS16(Bb + (size_t)row * K + k0 + col, &Bs[slot][u * 8]);
    }
  };

  f32x4 acc[8][4] = {};
  // prologue: tiles 0,1 in flight; wait only for tile 0 (vmcnt(4) leaves tile 1 flying)
  stage(0, 0);
  stage(1, 1);
  asm volatile("s_waitcnt vmcnt(4)" ::: "memory");
  __builtin_amdgcn_s_barrier();
  __builtin_amdgcn_sched_barrier(0);

  for (int t = 0; t < T; ++t) {
    int s = t & 1;
    bf16x8 bfr[4];
#pragma unroll
    for (int nt = 0; nt < 4; ++nt)
      bfr[nt] = *(const bf16x8*)&Bs[s][(wn * 64 + nt * 16 + lr) * BK + quad * 8];
#pragma unroll
    for (int mt = 0; mt < 8; ++mt) {
      bf16x8 af = *(const bf16x8*)&As[s][(wm * 128 + mt * 16 + lr) * BK + quad * 8];
#pragma unroll
      for (int nt = 0; nt < 4; ++nt)
        acc[mt][nt] = __builtin_amdgcn_mfma_f32_16x16x32_bf16(af, bfr[nt], acc[mt][nt], 0, 0, 0);
    }
    __builtin_amdgcn_sched_barrier(0);         // pin ds_reads above the barrier
    __builtin_amdgcn_s_barrier();              // all waves done reading slot s
    if (t + 2 < T) stage(s, t + 2);            // overwrite dead slot; loads fly across barriers
    if (t + 1 < T) {
      if (t + 2 < T) asm volatile("s_waitcnt vmcnt(4)" ::: "memory");   // t+1 landed
      else           asm volatile("s_waitcnt vmcnt(0)" ::: "memory");   // tail drain
      __builtin_amdgcn_s_barrier();            // cross-wave visibility of tile t+1
      __builtin_amdgcn_sched_barrier(0);       // pin next-iter ds_reads below
    }
  }

  int row0 = bm * 256 + wm * 128 + quad * 4;
  int col0 = bn * 256 + wn * 64 + lr;
  if (MODE == 4) {
#pragma unroll
    for (int mt = 0; mt < 8; ++mt)
#pragma unroll
      for (int r = 0; r < 4; ++r) {
        int row = row0 + mt * 16 + r;
        float rs = 0.f, rq = 0.f;
#pragma unroll
        for (int nt = 0; nt < 4; ++nt) {
          int col = col0 + nt * 16;
          size_t idx = (size_t)row * N + col;
          float o = acc[mt][nt][r] + bias[col] + res[idx];
          ((float*)outp)[idx] = o;
          rs += o; rq += o * o;
        }
#pragma unroll
        for (int off = 8; off >= 1; off >>= 1) {
          rs += __shfl_xor(rs, off, 64);
          rq += __shfl_xor(rq, off, 64);
        }
        if (lr == 0) {
          atomicAdd(&sacc[(size_t)row * 2], rs);
          atomicAdd(&sacc[(size_t)row * 2 + 1], rq);
        }
      }
  } else {
#pragma unroll
    for (int mt = 0; mt < 8; ++mt)
#pragma unroll
      for (int nt = 0; nt < 4; ++nt) {
        int col = col0 + nt * 16;
        float bv = bias[col];
#pragma unroll
        for (int r = 0; r < 4; ++r) {
          size_t idx = (size_t)(row0 + mt * 16 + r) * N + col;
          float v = acc[mt][nt][r] + bv;
          if (MODE == 0) ((bf16*)outp)[idx] = (bf16)fmaxf(v, 0.f);
          else ((float*)outp)[idx] = v + res[idx];
        }
      }
  }
}

// ---------------------------------------------------------------- 128x128 GEMM (kept for OUT)
// MODE 2: f32 out = .+bias; AF32 1: A fp32 staged via VGPR+convert
template <int N, int K, int MODE, int AF32>
__global__ __launch_bounds__(256) void gemm_bt(const void* __restrict__ A,
                                               const bf16* __restrict__ Bw,
                                               const float* __restrict__ bias,
                                               const float* __restrict__ res,
                                               void* __restrict__ outp) {
  constexpr int BK = 64;
  __shared__ __align__(16) bf16 As[128 * BK];
  __shared__ __align__(16) bf16 Bs[128 * BK];
  int tid = threadIdx.x;
  int bn = blockIdx.x, bm = blockIdx.y;
  if ((gridDim.y & 7) == 0) {
    int gx = gridDim.x, gy = gridDim.y;
    int h = bm * gx + bn;
    int x = h & 7, k = h >> 3;
    int gpc = gy >> 3;
    bm = x * gpc + k / gx;
    bn = k - (k / gx) * gx;
  }
  const bf16* Abf = (const bf16*)A + (size_t)bm * 128 * K;
  const float* Af = (const float*)A + (size_t)bm * 128 * K;
  const bf16* Bb = Bw + (size_t)bn * 128 * K;
  int lane = tid & 63, wave = tid >> 6;
  int wm = (wave >> 1) * 64, wn = (wave & 1) * 64;
  int lr = lane & 15, quad = lane >> 4;
  f32x4 acc[4][4] = {};
  for (int k0 = 0; k0 < K; k0 += BK) {
    if (AF32) {
#pragma unroll
      for (int r = 0; r < 8; ++r) {
        int c = r * 256 + tid;
        int row = c >> 4, col4 = (c & 15) * 4;
        float4 f = *(const float4*)(Af + (size_t)row * K + k0 + col4);
        bf16x4 o = {(bf16)f.x, (bf16)f.y, (bf16)f.z, (bf16)f.w};
        *(bf16x4*)&As[row * BK + col4] = o;
      }
    } else {
#pragma unroll
      for (int r = 0; r < 4; ++r) {
        int c = r * 256 + tid;
        int row = c >> 3, col = (c & 7) * 8;
        GLD_LDS16(Abf + (size_t)row * K + k0 + col, &As[c * 8]);
      }
    }
#pragma unroll
    for (int r = 0; r < 4; ++r) {
      int c = r * 256 + tid;
      int row = c >> 3, col = (c & 7) * 8;
      GLD_LDS16(Bb + (size_t)row * K + k0 + col, &Bs[c * 8]);
    }
    __syncthreads();
#pragma unroll
    for (int kt = 0; kt < 2; ++kt) {
      bf16x8 af[4], bfr[4];
#pragma unroll
      for (int mt = 0; mt < 4; ++mt) af[mt] = *(const bf16x8*)&As[(wm + mt * 16 + lr) * BK + kt * 32 + quad * 8];
#pragma unroll
      for (int nt = 0; nt < 4; ++nt) bfr[nt] = *(const bf16x8*)&Bs[(wn + nt * 16 + lr) * BK + kt * 32 + quad * 8];
#pragma unroll
      for (int mt = 0; mt < 4; ++mt)
#pragma unroll
        for (int nt = 0; nt < 4; ++nt)
          acc[mt][nt] = __builtin_amdgcn_mfma_f32_16x16x32_bf16(af[mt], bfr[nt], acc[mt][nt], 0, 0, 0);
    }
    __syncthreads();
  }
  int row0 = bm * 128 + wm + quad * 4;
  int col0 = bn * 128 + wn + lr;
#pragma unroll
  for (int mt = 0; mt < 4; ++mt)
#pragma unroll
    for (int nt = 0; nt < 4; ++nt) {
      int col = col0 + nt * 16;
      float bv = bias[col];
#pragma unroll
      for (int r = 0; r < 4; ++r) {
        size_t idx = (size_t)(row0 + mt * 16 + r) * N + col;
        float v = acc[mt][nt][r] + bv;
        if (MODE == 0) ((bf16*)outp)[idx] = (bf16)fmaxf(v, 0.f);
        else if (MODE == 1) ((float*)outp)[idx] = v + res[idx];
        else ((float*)outp)[idx] = v;
      }
    }
}

// ---------------------------------------------------------------- launch
extern "C" void kernel_launch(void* const* d_in, const int* in_sizes, int n_in,
                              void* d_out, int out_size, void* d_ws, size_t ws_size,
                              hipStream_t stream) {
  const float* batch   = (const float*)d_in[0];
  const float* W_patch = (const float*)d_in[1];
  const float* b_patch = (const float*)d_in[2];
  const float* pos     = (const float*)d_in[3];
  const float* ln1_g   = (const float*)d_in[4];
  const float* ln1_b   = (const float*)d_in[5];
  const float* Wq      = (const float*)d_in[6];
  const float* bq      = (const float*)d_in[7];
  const float* Wk      = (const float*)d_in[8];
  const float* bk      = (const float*)d_in[9];
  const float* Wv      = (const float*)d_in[10];
  const float* bv      = (const float*)d_in[11];
  const float* ln2_g   = (const float*)d_in[12];
  const float* ln2_b   = (const float*)d_in[13];
  const float* W1      = (const float*)d_in[14];
  const float* b1      = (const float*)d_in[15];
  const float* W2      = (const float*)d_in[16];
  const float* b2      = (const float*)d_in[17];
  const float* W_out   = (const float*)d_in[18];
  const float* b_out   = (const float*)d_in[19];
  float* out = (float*)d_out;
  (void)bk;   // folded out: softmax-invariant terms

  char* ws = (char*)d_ws;
  size_t off = 0;
  float* z     = (float*)(ws + off); off += (size_t)M * D * 4;        // 169,869,312
  float* stats = (float*)(ws + off); off += (size_t)M * 2 * 4;
  float* sacc  = (float*)(ws + off); off += (size_t)M * 2 * 4;
  bf16* wqk_b = (bf16*)(ws + off);   off += (size_t)4 * H * 4096 * 2; // Wq^T Wk, bf16
  bf16* wv_b = (bf16*)(ws + off);    off += (size_t)4 * H * 4096 * 2;
  float* vk_f = (float*)(ws + off);  off += (size_t)4 * H * 64 * 4;   // Wk^T bq, f32
  bf16* w1_b = (bf16*)(ws + off);    off += (size_t)4 * DFF * D * 2;
  bf16* w2_b = (bf16*)(ws + off);    off += (size_t)4 * D * DFF * 2;
  bf16* wo_b = (bf16*)(ws + off);    off += (size_t)OUTD * D * 2;

  // per-chunk: act (rc x DFF bf16) + zbc (rc x D bf16, LN2 bf16 mirror for GEMM1's A).
  // rc multiple of 2048 => grid.y = rc/256 multiple of 8 (swizzle active, clean tiles).
  size_t avail = ws_size > off ? ws_size - off : (size_t)0;
  long long rcl = (long long)(avail / ((size_t)(DFF + D) * 2));
  int rc = (rcl > (long long)M) ? M : (int)rcl;
  rc = (rc / 2048) * 2048;
  if (rc <= 0) rc = 2048;
  bf16* act = (bf16*)(ws + off);  off += (size_t)rc * DFF * 2;
  bf16* zbc = (bf16*)(ws + off);

  qk_prep<<<48, 64, 0, stream>>>(Wq, Wk, bq, wqk_b, vk_f);
  f2b_kernel<<<192, 256, 0, stream>>>(Wv, wv_b, 49152);
  f2b_kernel<<<4608, 256, 0, stream>>>(W1, w1_b, 1179648);
  f2b_kernel<<<4608, 256, 0, stream>>>(W2, w2_b, 1179648);
  f2b_kernel<<<192, 256, 0, stream>>>(W_out, wo_b, 49152);

  patch_embed<<<BC, 256, 0, stream>>>(batch, W_patch, b_patch, pos, z);
  ln_stats<<<M / 4, 256, 0, stream>>>(z, stats);                       // LN1 stats, layer 0

  for (int l = 0; l < 4; ++l) {
    attn_kernel<<<dim3(H, BC), 64, 0, stream>>>(z, stats, ln1_g + l * D, ln1_b + l * D,
        wqk_b + (size_t)l * H * 4096, wv_b + (size_t)l * H * 4096,
        vk_f + (size_t)l * H * 64, bv + (size_t)l * H * 64, z);
    if (l < 3) zerok<<<(M * 2 + 255) / 256, 256, 0, stream>>>(sacc, M * 2);
    for (int m0 = 0; m0 < M; m0 += rc) {
      int mr = (M - m0 < rc) ? (M - m0) : rc;
      ln_inplace<<<mr / 4, 256, 0, stream>>>(z + (size_t)m0 * D, ln2_g + l * D,
                                             ln2_b + l * D, zbc);
      gemm256<DFF, D, 0><<<dim3(DFF / 256, mr / 256), 512, 0, stream>>>(
          zbc, w1_b + (size_t)l * DFF * D, b1 + l * DFF, nullptr, act, nullptr);
      if (l < 3)
        gemm256<D, DFF, 4><<<dim3(D / 256, mr / 256), 512, 0, stream>>>(
            act, w2_b + (size_t)l * D * DFF, b2 + l * D, z + (size_t)m0 * D,
            z + (size_t)m0 * D, sacc + (size_t)m0 * 2);
      else
        gemm256<D, DFF, 1><<<dim3(D / 256, mr / 256), 512, 0, stream>>>(
            act, w2_b + (size_t)l * D * DFF, b2 + l * D, z + (size_t)m0 * D,
            z + (size_t)m0 * D, nullptr);
    }
    if (l < 3) stats_fin<<<(M + 255) / 256, 256, 0, stream>>>(sacc, stats, M);
  }

  gemm_bt<OUTD, D, 2, 1><<<dim3(OUTD / 128, M / 128), 256, 0, stream>>>(
      z, wo_b, b_out, nullptr, out);
}

// Round 9
// 3249.498 us; speedup vs baseline: 1.1105x; 1.1105x over previous
//
#include <hip/hip_runtime.h>
#include <hip/hip_bf16.h>
#include <cstdint>
#include <cstddef>

typedef __bf16 bf16;
typedef bf16 bf16x8 __attribute__((ext_vector_type(8)));
typedef bf16 bf16x4 __attribute__((ext_vector_type(4)));
typedef float f32x4 __attribute__((ext_vector_type(4)));
typedef unsigned int u32;

#define GLD_LDS16(gptr, lptr)                                                        \
  __builtin_amdgcn_global_load_lds((const __attribute__((address_space(1))) u32*)(gptr), \
                                   (__attribute__((address_space(3))) u32*)(lptr), 16, 0, 0)

// single-wave-block phase fence: LDS ops are in-order per wave, so a full barrier is
// overkill — wait LDS only, keep global loads (epilogue prefetch) in flight.
#define WAVE_FENCE()  do { asm volatile("s_waitcnt lgkmcnt(0)" ::: "memory"); \
                           __builtin_amdgcn_sched_barrier(0); } while (0)

static constexpr int S = 36, D = 768, H = 12, HD = 64, DFF = 1536;
static constexpr int BC = 1536;        // B*C images
static constexpr int M = BC * S;       // 55296 tokens
static constexpr int OUTD = 256;

// ---------------------------------------------------------------- fp32 -> bf16
__global__ __launch_bounds__(256) void f2b_kernel(const float* __restrict__ in,
                                                  bf16* __restrict__ out, int n4) {
  int i = blockIdx.x * 256 + threadIdx.x;
  if (i < n4) {
    float4 f = ((const float4*)in)[i];
    bf16x4 o = {(bf16)f.x, (bf16)f.y, (bf16)f.z, (bf16)f.w};
    ((bf16x4*)out)[i] = o;
  }
}

// ---------------------------------------------------------------- zero / stats finalize
__global__ __launch_bounds__(256) void zerok(float* __restrict__ p, int n) {
  int i = blockIdx.x * 256 + threadIdx.x;
  if (i < n) p[i] = 0.f;
}
// finalize (mean, rstd) and re-zero sacc for the next layer's accumulation
__global__ __launch_bounds__(256) void stats_fin(float* __restrict__ sacc,
                                                 float* __restrict__ stats, int n) {
  int i = blockIdx.x * 256 + threadIdx.x;
  if (i < n) {
    float sm = sacc[(size_t)i * 2] * (1.f / 768.f);
    float sq = sacc[(size_t)i * 2 + 1] * (1.f / 768.f);
    float var = sq - sm * sm;
    stats[(size_t)i * 2] = sm;
    stats[(size_t)i * 2 + 1] = rsqrtf(var + 1e-5f);
    sacc[(size_t)i * 2] = 0.f;
    sacc[(size_t)i * 2 + 1] = 0.f;
  }
}

// ---------------------------------------------------------------- Wqk = Wq^T Wk, vk = Wk^T bq
__global__ __launch_bounds__(64) void qk_prep(const float* __restrict__ Wq,
                                              const float* __restrict__ Wk,
                                              const float* __restrict__ bq,
                                              bf16* __restrict__ wb,
                                              float* __restrict__ vkout) {
  int lh = blockIdx.x;                 // 0..47 = l*12+h
  int e = threadIdx.x;                 // 0..63
  __shared__ float Wqs[64][64];        // [f][d]
  __shared__ float Wks[64][64];        // [f][e]
  const float* wqp = Wq + (size_t)lh * 4096;
  const float* wkp = Wk + (size_t)lh * 4096;
  for (int i = e; i < 4096; i += 64) {
    Wqs[i >> 6][i & 63] = wqp[i];
    Wks[i >> 6][i & 63] = wkp[i];
  }
  __syncthreads();
  float ks[64];
#pragma unroll
  for (int f = 0; f < 64; ++f) ks[f] = Wks[f][e];
  for (int d0 = 0; d0 < 64; d0 += 4) {
    float a0 = 0.f, a1 = 0.f, a2 = 0.f, a3 = 0.f;
#pragma unroll
    for (int f = 0; f < 64; ++f) {
      float4 wq4 = *(const float4*)&Wqs[f][d0];   // broadcast read
      a0 += wq4.x * ks[f]; a1 += wq4.y * ks[f];
      a2 += wq4.z * ks[f]; a3 += wq4.w * ks[f];
    }
    bf16x4 o = {(bf16)a0, (bf16)a1, (bf16)a2, (bf16)a3};
    *(bf16x4*)&wb[(size_t)lh * 4096 + e * 64 + d0] = o;
  }
  const float* bqp = bq + lh * 64;
  float acc = 0.f;
#pragma unroll
  for (int f = 0; f < 64; ++f) acc += ks[f] * bqp[f];
  vkout[lh * 64 + e] = acc;
}

// ---------------------------------------------------------------- patch embed
__global__ __launch_bounds__(256) void patch_embed(const float* __restrict__ batch,
                                                   const float* __restrict__ Wp,
                                                   const float* __restrict__ bp,
                                                   const float* __restrict__ pos,
                                                   float* __restrict__ z) {
  int bc = blockIdx.x, tid = threadIdx.x;
  __shared__ float p[36][40];          // [token][pixel], padded row
  for (int i = tid; i < 1296; i += 256) {
    float f = batch[(size_t)bc * 1296 + i];
    int row = i / 36, col = i - row * 36;
    p[(row / 6) * 6 + col / 6][(row % 6) * 6 + (col % 6)] = f;
  }
  __syncthreads();
  for (int c0 = 0; c0 < 768; c0 += 256) {
    int d = c0 + tid;
    float wr[36];
    const float4* wp4 = (const float4*)(Wp + (size_t)d * 36);   // 144B rows, 16B aligned
#pragma unroll
    for (int q = 0; q < 9; ++q) {
      float4 f = wp4[q];
      wr[q * 4] = f.x; wr[q * 4 + 1] = f.y; wr[q * 4 + 2] = f.z; wr[q * 4 + 3] = f.w;
    }
    float gb = bp[d];
    for (int s = 0; s < 36; ++s) {
      float acc = 0.f;
#pragma unroll
      for (int k = 0; k < 36; ++k) acc += p[s][k] * wr[k];
      z[((size_t)bc * 36 + s) * 768 + d] = acc + gb + pos[s * 768 + d];
    }
  }
}

// ---------------------------------------------------------------- LN stats (mean, rstd) per row
__global__ __launch_bounds__(256) void ln_stats(const float* __restrict__ zin,
                                                float* __restrict__ stats) {
  int row = blockIdx.x * 4 + (threadIdx.x >> 6);
  int lane = threadIdx.x & 63;
  const float* zr = zin + (size_t)row * D;
  float x[12];
#pragma unroll
  for (int i = 0; i < 12; ++i) x[i] = zr[i * 64 + lane];
  float s = 0.f;
#pragma unroll
  for (int i = 0; i < 12; ++i) s += x[i];
#pragma unroll
  for (int off = 32; off >= 1; off >>= 1) s += __shfl_xor(s, off, 64);
  float m = s * (1.f / 768.f);
  float v = 0.f;
#pragma unroll
  for (int i = 0; i < 12; ++i) { float dd = x[i] - m; v += dd * dd; }
#pragma unroll
  for (int off = 32; off >= 1; off >>= 1) v += __shfl_xor(v, off, 64);
  v *= (1.f / 768.f);
  if (lane == 0) {
    stats[(size_t)row * 2] = m;
    stats[(size_t)row * 2 + 1] = rsqrtf(v + 1e-5f);
  }
}

// ---------------------------------------------------------------- LN in-place (fp32)
__global__ __launch_bounds__(256) void ln_inplace(float* __restrict__ z,
                                                  const float* __restrict__ g,
                                                  const float* __restrict__ bt) {
  int row = blockIdx.x * 4 + (threadIdx.x >> 6);
  int lane = threadIdx.x & 63;
  float* zr = z + (size_t)row * D;
  float x[12];
#pragma unroll
  for (int i = 0; i < 12; ++i) x[i] = zr[i * 64 + lane];
  float s = 0.f;
#pragma unroll
  for (int i = 0; i < 12; ++i) s += x[i];
#pragma unroll
  for (int off = 32; off >= 1; off >>= 1) s += __shfl_xor(s, off, 64);
  float m = s * (1.f / 768.f);
  float v = 0.f;
#pragma unroll
  for (int i = 0; i < 12; ++i) { float dd = x[i] - m; v += dd * dd; }
#pragma unroll
  for (int off = 32; off >= 1; off >>= 1) v += __shfl_xor(v, off, 64);
  v *= (1.f / 768.f);
  float rstd = rsqrtf(v + 1e-5f);
#pragma unroll
  for (int i = 0; i < 12; ++i) {
    int d = i * 64 + lane;
    zr[d] = (x[i] - m) * rstd * g[d] + bt[d];
  }
}

// ---------------------------------------------------------------- fused attention (G-trick)
// R9 (latency-chain edition): single-wave block, so the 3 __syncthreads (each forcing
// a vmcnt(0) drain) are replaced by LDS-only fences; the epilogue z reads are
// prefetched right after the hfrag build (latency hides under 90 MFMAs); MFMA
// clusters run at setprio(1) so this wave's matrix ops preempt other blocks' loads.
__global__ __launch_bounds__(64) void attn_kernel(const float* __restrict__ zg,
                                                  const float* __restrict__ stats,
                                                  const float* __restrict__ g1,
                                                  const float* __restrict__ b1_,
                                                  const bf16* __restrict__ Wqk,
                                                  const bf16* __restrict__ Wv,
                                                  const float* __restrict__ vk,
                                                  const float* __restrict__ bv,
                                                  float* __restrict__ z) {
  int head = blockIdx.x;
  int bc = blockIdx.y;
  __shared__ __align__(16) bf16 gb[48 * 72];   // G, later P
  __shared__ __align__(16) bf16 vt[64 * 72];   // vt[e][t]
  int lane = threadIdx.x;
  int lr = lane & 15, quad = lane >> 4;

#pragma unroll
  for (int t0 = 0; t0 < 16; ++t0) vt[lane * 72 + 48 + t0] = (bf16)0.f;

  const float* zsrc = zg + ((size_t)bc * S) * D + head * HD;
  const float* st = stats + (size_t)bc * S * 2;

  float gv[2][8], bvv[2][8];
#pragma unroll
  for (int kt = 0; kt < 2; ++kt) {
    int c0 = head * HD + kt * 32 + quad * 8;
    float4 ga = *(const float4*)(g1 + c0);
    float4 gb2 = *(const float4*)(g1 + c0 + 4);
    float4 ba = *(const float4*)(b1_ + c0);
    float4 bb2 = *(const float4*)(b1_ + c0 + 4);
    gv[kt][0] = ga.x; gv[kt][1] = ga.y; gv[kt][2] = ga.z; gv[kt][3] = ga.w;
    gv[kt][4] = gb2.x; gv[kt][5] = gb2.y; gv[kt][6] = gb2.z; gv[kt][7] = gb2.w;
    bvv[kt][0] = ba.x; bvv[kt][1] = ba.y; bvv[kt][2] = ba.z; bvv[kt][3] = ba.w;
    bvv[kt][4] = bb2.x; bvv[kt][5] = bb2.y; bvv[kt][6] = bb2.z; bvv[kt][7] = bb2.w;
  }

  bf16x8 hfrag[3][2];
#pragma unroll
  for (int mt = 0; mt < 3; ++mt) {
    int srow = mt * 16 + lr;
    if (srow < 36) {
      float mm = st[srow * 2], rr = st[srow * 2 + 1];
#pragma unroll
      for (int kt = 0; kt < 2; ++kt) {
        int c0 = kt * 32 + quad * 8;
        float4 f0 = *(const float4*)(zsrc + (size_t)srow * D + c0);
        float4 f1 = *(const float4*)(zsrc + (size_t)srow * D + c0 + 4);
        float hv[8] = {f0.x, f0.y, f0.z, f0.w, f1.x, f1.y, f1.z, f1.w};
        bf16x8 o;
#pragma unroll
        for (int j = 0; j < 8; ++j) o[j] = (bf16)((hv[j] - mm) * rr * gv[kt][j] + bvv[kt][j]);
        hfrag[mt][kt] = o;
      }
    } else {
#pragma unroll
      for (int kt = 0; kt < 2; ++kt) {
        bf16x8 o;
#pragma unroll
        for (int j = 0; j < 8; ++j) o[j] = (bf16)0.f;
        hfrag[mt][kt] = o;
      }
    }
  }

  // epilogue z prefetch: issue the ~36 reads now; ~600cy latency hides under the
  // 90 MFMAs + softmax below. Values are stable (blocks write disjoint slices).
  float zv[3][4][4];
#pragma unroll
  for (int mt = 0; mt < 3; ++mt)
#pragma unroll
    for (int nt = 0; nt < 4; ++nt)
#pragma unroll
      for (int r = 0; r < 4; ++r) {
        int s2 = mt * 16 + quad * 4 + r;
        zv[mt][nt][r] = (s2 < 36) ? zsrc[(size_t)s2 * D + nt * 16 + lr] : 0.f;
      }

  float vkv[2][8];
#pragma unroll
  for (int kt = 0; kt < 2; ++kt) {
    int c0 = head * 64 + kt * 32 + quad * 8;
    float4 va = *(const float4*)(vk + c0);
    float4 vb2 = *(const float4*)(vk + c0 + 4);
    vkv[kt][0] = va.x; vkv[kt][1] = va.y; vkv[kt][2] = va.z; vkv[kt][3] = va.w;
    vkv[kt][4] = vb2.x; vkv[kt][5] = vb2.y; vkv[kt][6] = vb2.z; vkv[kt][7] = vb2.w;
  }
  float tv[3];
#pragma unroll
  for (int mt = 0; mt < 3; ++mt) {
    float sp = 0.f;
#pragma unroll
    for (int kt = 0; kt < 2; ++kt)
#pragma unroll
      for (int j = 0; j < 8; ++j) sp += (float)hfrag[mt][kt][j] * vkv[kt][j];
    sp += __shfl_xor(sp, 16, 64);
    sp += __shfl_xor(sp, 32, 64);
    tv[mt] = sp;
  }

  const bf16* Wm[2] = {Wqk + (size_t)head * 4096, Wv + (size_t)head * 4096};
  const float* bvp = bv + head * 64;
  for (int p = 0; p < 2; ++p) {
    bf16x8 bfr[4][2];
#pragma unroll
    for (int nt = 0; nt < 4; ++nt)
#pragma unroll
      for (int kt = 0; kt < 2; ++kt)
        bfr[nt][kt] = *(const bf16x8*)(Wm[p] + (nt * 16 + lr) * 64 + kt * 32 + quad * 8);
#pragma unroll
    for (int mt = 0; mt < 3; ++mt) {
      f32x4 acc[4] = {};
      __builtin_amdgcn_s_setprio(1);
#pragma unroll
      for (int kt = 0; kt < 2; ++kt)
#pragma unroll
        for (int nt = 0; nt < 4; ++nt)
          acc[nt] = __builtin_amdgcn_mfma_f32_16x16x32_bf16(hfrag[mt][kt], bfr[nt][kt], acc[nt], 0, 0, 0);
      __builtin_amdgcn_s_setprio(0);
#pragma unroll
      for (int nt = 0; nt < 4; ++nt) {
        float bb = (p == 1) ? bvp[nt * 16 + lr] : 0.f;
#pragma unroll
        for (int r = 0; r < 4; ++r) {
          int s2 = mt * 16 + quad * 4 + r;
          int e = nt * 16 + lr;
          float val = acc[nt][r] + bb;
          if (p == 0) gb[s2 * 72 + e] = (bf16)val;
          else vt[e * 72 + s2] = (bf16)val;
        }
      }
    }
  }
  WAVE_FENCE();                         // LDS writes visible to own-wave reads

  f32x4 sc[3][3];
#pragma unroll
  for (int mt = 0; mt < 3; ++mt)
#pragma unroll
    for (int nt = 0; nt < 3; ++nt) {
      f32x4 a = {};
      __builtin_amdgcn_s_setprio(1);
#pragma unroll
      for (int kt = 0; kt < 2; ++kt) {
        bf16x8 af = *(const bf16x8*)&gb[(mt * 16 + lr) * 72 + kt * 32 + quad * 8];
        a = __builtin_amdgcn_mfma_f32_16x16x32_bf16(af, hfrag[nt][kt], a, 0, 0, 0);
      }
      __builtin_amdgcn_s_setprio(0);
      int t = nt * 16 + lr;
#pragma unroll
      for (int r = 0; r < 4; ++r) {
        float v = (a[r] + tv[nt]) * 0.125f;     // 1/sqrt(64)
        if (t >= 36) v = -1e30f;
        sc[mt][nt][r] = v;
      }
    }
  WAVE_FENCE();                         // scores' gb reads done before P overwrites

#pragma unroll
  for (int mt = 0; mt < 3; ++mt) {
    float mx[4], sum[4];
#pragma unroll
    for (int r = 0; r < 4; ++r)
      mx[r] = fmaxf(fmaxf(sc[mt][0][r], sc[mt][1][r]), sc[mt][2][r]);
#pragma unroll
    for (int r = 0; r < 4; ++r)
#pragma unroll
      for (int off = 8; off >= 1; off >>= 1) mx[r] = fmaxf(mx[r], __shfl_xor(mx[r], off, 64));
#pragma unroll
    for (int r = 0; r < 4; ++r) sum[r] = 0.f;
#pragma unroll
    for (int nt = 0; nt < 3; ++nt)
#pragma unroll
      for (int r = 0; r < 4; ++r) {
        float e = __expf(sc[mt][nt][r] - mx[r]);
        sc[mt][nt][r] = e;
        sum[r] += e;
      }
#pragma unroll
    for (int r = 0; r < 4; ++r)
#pragma unroll
      for (int off = 8; off >= 1; off >>= 1) sum[r] += __shfl_xor(sum[r], off, 64);
#pragma unroll
    for (int nt = 0; nt < 4; ++nt)
#pragma unroll
      for (int r = 0; r < 4; ++r) {
        int s2 = mt * 16 + quad * 4 + r;
        int t = nt * 16 + lr;
        float pv = (nt < 3) ? sc[mt][nt][r] / sum[r] : 0.f;
        gb[s2 * 72 + t] = (bf16)pv;
      }
  }
  WAVE_FENCE();                         // P writes visible to own-wave PV reads

#pragma unroll
  for (int mt = 0; mt < 3; ++mt) {
    f32x4 o[4] = {};
    __builtin_amdgcn_s_setprio(1);
#pragma unroll
    for (int kt = 0; kt < 2; ++kt) {
      bf16x8 a = *(const bf16x8*)&gb[(mt * 16 + lr) * 72 + kt * 32 + quad * 8];
#pragma unroll
      for (int nt = 0; nt < 4; ++nt) {
        bf16x8 b = *(const bf16x8*)&vt[(nt * 16 + lr) * 72 + kt * 32 + quad * 8];
        o[nt] = __builtin_amdgcn_mfma_f32_16x16x32_bf16(a, b, o[nt], 0, 0, 0);
      }
    }
    __builtin_amdgcn_s_setprio(0);
#pragma unroll
    for (int nt = 0; nt < 4; ++nt)
#pragma unroll
      for (int r = 0; r < 4; ++r) {
        int s2 = mt * 16 + quad * 4 + r;
        if (s2 < 36) {
          int e = nt * 16 + lr;
          size_t idx = ((size_t)bc * S + s2) * D + head * HD + e;
          z[idx] = zv[mt][nt][r] + o[nt][r];    // prefetched read: pure store here
        }
      }
  }
}

// ---------------------------------------------------------------- GEMM (B^T layout)
// R7-verified two-barrier loop + XCD-aware bijective swizzle + MODE 4 fused LN1 stats.
// MODE 0: bf16 relu(.+bias); MODE 1: f32 .+bias+res; MODE 2: f32 .+bias;
// MODE 4: MODE1 + per-row sum/sumsq atomics. AF32 1: A fp32 via VGPR+convert.
template <int N, int K, int MODE, int AF32>
__global__ __launch_bounds__(256) void gemm_bt(const void* __restrict__ A,
                                               const bf16* __restrict__ Bw,
                                               const float* __restrict__ bias,
                                               const float* __restrict__ res,
                                               void* __restrict__ outp,
                                               float* __restrict__ sacc) {
  constexpr int BK = 64;
  __shared__ __align__(16) bf16 As[128 * BK];
  __shared__ __align__(16) bf16 Bs[128 * BK];
  int tid = threadIdx.x;
  int bn = blockIdx.x, bm = blockIdx.y;
  if ((gridDim.y & 7) == 0) {
    int gx = gridDim.x, gy = gridDim.y;
    int h = bm * gx + bn;
    int x = h & 7, k = h >> 3;
    int gpc = gy >> 3;                 // bm-groups per class
    bm = x * gpc + k / gx;
    bn = k - (k / gx) * gx;
  }
  const bf16* Abf = (const bf16*)A + (size_t)bm * 128 * K;
  const float* Af = (const float*)A + (size_t)bm * 128 * K;
  const bf16* Bb = Bw + (size_t)bn * 128 * K;
  int lane = tid & 63, wave = tid >> 6;
  int wm = (wave >> 1) * 64, wn = (wave & 1) * 64;
  int lr = lane & 15, quad = lane >> 4;
  f32x4 acc[4][4] = {};
  for (int k0 = 0; k0 < K; k0 += BK) {
    if (AF32) {
#pragma unroll
      for (int r = 0; r < 8; ++r) {
        int c = r * 256 + tid;            // 0..2047 float4-units
        int row = c >> 4, col4 = (c & 15) * 4;
        float4 f = *(const float4*)(Af + (size_t)row * K + k0 + col4);
        bf16x4 o = {(bf16)f.x, (bf16)f.y, (bf16)f.z, (bf16)f.w};
        *(bf16x4*)&As[row * BK + col4] = o;
      }
    } else {
#pragma unroll
      for (int r = 0; r < 4; ++r) {
        int c = r * 256 + tid;
        int row = c >> 3, col = (c & 7) * 8;
        GLD_LDS16(Abf + (size_t)row * K + k0 + col, &As[c * 8]);
      }
    }
#pragma unroll
    for (int r = 0; r < 4; ++r) {
      int c = r * 256 + tid;
      int row = c >> 3, col = (c & 7) * 8;
      GLD_LDS16(Bb + (size_t)row * K + k0 + col, &Bs[c * 8]);
    }
    __syncthreads();
#pragma unroll
    for (int kt = 0; kt < 2; ++kt) {
      bf16x8 af[4], bfr[4];
#pragma unroll
      for (int mt = 0; mt < 4; ++mt) af[mt] = *(const bf16x8*)&As[(wm + mt * 16 + lr) * BK + kt * 32 + quad * 8];
#pragma unroll
      for (int nt = 0; nt < 4; ++nt) bfr[nt] = *(const bf16x8*)&Bs[(wn + nt * 16 + lr) * BK + kt * 32 + quad * 8];
#pragma unroll
      for (int mt = 0; mt < 4; ++mt)
#pragma unroll
        for (int nt = 0; nt < 4; ++nt)
          acc[mt][nt] = __builtin_amdgcn_mfma_f32_16x16x32_bf16(af[mt], bfr[nt], acc[mt][nt], 0, 0, 0);
    }
    __syncthreads();
  }
  int row0 = bm * 128 + wm + quad * 4;
  int col0 = bn * 128 + wn + lr;
  if (MODE == 4) {
#pragma unroll
    for (int mt = 0; mt < 4; ++mt)
#pragma unroll
      for (int r = 0; r < 4; ++r) {
        int row = row0 + mt * 16 + r;
        float rs = 0.f, rq = 0.f;
#pragma unroll
        for (int nt = 0; nt < 4; ++nt) {
          int col = col0 + nt * 16;
          size_t idx = (size_t)row * N + col;
          float o = acc[mt][nt][r] + bias[col] + res[idx];
          ((float*)outp)[idx] = o;
          rs += o; rq += o * o;
        }
#pragma unroll
        for (int off = 8; off >= 1; off >>= 1) {
          rs += __shfl_xor(rs, off, 64);
          rq += __shfl_xor(rq, off, 64);
        }
        if (lr == 0) {
          atomicAdd(&sacc[(size_t)row * 2], rs);
          atomicAdd(&sacc[(size_t)row * 2 + 1], rq);
        }
      }
  } else {
#pragma unroll
    for (int mt = 0; mt < 4; ++mt)
#pragma unroll
      for (int nt = 0; nt < 4; ++nt) {
        int col = col0 + nt * 16;
        float bv = bias[col];
#pragma unroll
        for (int r = 0; r < 4; ++r) {
          size_t idx = (size_t)(row0 + mt * 16 + r) * N + col;
          float v = acc[mt][nt][r] + bv;
          if (MODE == 0) ((bf16*)outp)[idx] = (bf16)fmaxf(v, 0.f);
          else if (MODE == 1) ((float*)outp)[idx] = v + res[idx];
          else ((float*)outp)[idx] = v;
        }
      }
  }
}

// ---------------------------------------------------------------- launch
extern "C" void kernel_launch(void* const* d_in, const int* in_sizes, int n_in,
                              void* d_out, int out_size, void* d_ws, size_t ws_size,
                              hipStream_t stream) {
  const float* batch   = (const float*)d_in[0];
  const float* W_patch = (const float*)d_in[1];
  const float* b_patch = (const float*)d_in[2];
  const float* pos     = (const float*)d_in[3];
  const float* ln1_g   = (const float*)d_in[4];
  const float* ln1_b   = (const float*)d_in[5];
  const float* Wq      = (const float*)d_in[6];
  const float* bq      = (const float*)d_in[7];
  const float* Wk      = (const float*)d_in[8];
  const float* bk      = (const float*)d_in[9];
  const float* Wv      = (const float*)d_in[10];
  const float* bv      = (const float*)d_in[11];
  const float* ln2_g   = (const float*)d_in[12];
  const float* ln2_b   = (const float*)d_in[13];
  const float* W1      = (const float*)d_in[14];
  const float* b1      = (const float*)d_in[15];
  const float* W2      = (const float*)d_in[16];
  const float* b2      = (const float*)d_in[17];
  const float* W_out   = (const float*)d_in[18];
  const float* b_out   = (const float*)d_in[19];
  float* out = (float*)d_out;
  (void)bk;   // folded out: softmax-invariant terms

  char* ws = (char*)d_ws;
  size_t off = 0;
  float* z     = (float*)(ws + off); off += (size_t)M * D * 4;        // 169,869,312
  float* stats = (float*)(ws + off); off += (size_t)M * 2 * 4;
  float* sacc  = (float*)(ws + off); off += (size_t)M * 2 * 4;
  bf16* wqk_b = (bf16*)(ws + off);   off += (size_t)4 * H * 4096 * 2; // Wq^T Wk, bf16
  bf16* wv_b = (bf16*)(ws + off);    off += (size_t)4 * H * 4096 * 2;
  float* vk_f = (float*)(ws + off);  off += (size_t)4 * H * 64 * 4;   // Wk^T bq, f32
  bf16* w1_b = (bf16*)(ws + off);    off += (size_t)4 * DFF * D * 2;
  bf16* w2_b = (bf16*)(ws + off);    off += (size_t)4 * D * DFF * 2;
  bf16* wo_b = (bf16*)(ws + off);    off += (size_t)OUTD * D * 2;
  bf16* act  = (bf16*)(ws + off);    // remainder, chunked

  size_t avail = ws_size > off ? ws_size - off : (size_t)0;
  long long rcl = (long long)(avail / ((size_t)DFF * 2));
  int rc = (rcl > (long long)M) ? M : (int)rcl;
  rc = (rc / 1024) * 1024;             // x1024 keeps gridDim.y%8==0 -> swizzle active
  if (rc <= 0) rc = 128;

  qk_prep<<<48, 64, 0, stream>>>(Wq, Wk, bq, wqk_b, vk_f);
  f2b_kernel<<<192, 256, 0, stream>>>(Wv, wv_b, 49152);
  f2b_kernel<<<4608, 256, 0, stream>>>(W1, w1_b, 1179648);
  f2b_kernel<<<4608, 256, 0, stream>>>(W2, w2_b, 1179648);
  f2b_kernel<<<192, 256, 0, stream>>>(W_out, wo_b, 49152);

  patch_embed<<<BC, 256, 0, stream>>>(batch, W_patch, b_patch, pos, z);
  ln_stats<<<M / 4, 256, 0, stream>>>(z, stats);                       // LN1 stats, layer 0
  zerok<<<(M * 2 + 255) / 256, 256, 0, stream>>>(sacc, M * 2);         // once; stats_fin re-zeros

  for (int l = 0; l < 4; ++l) {
    attn_kernel<<<dim3(H, BC), 64, 0, stream>>>(z, stats, ln1_g + l * D, ln1_b + l * D,
        wqk_b + (size_t)l * H * 4096, wv_b + (size_t)l * H * 4096,
        vk_f + (size_t)l * H * 64, bv + (size_t)l * H * 64, z);
    ln_inplace<<<M / 4, 256, 0, stream>>>(z, ln2_g + l * D, ln2_b + l * D);
    for (int m0 = 0; m0 < M; m0 += rc) {
      int mr = (M - m0 < rc) ? (M - m0) : rc;
      gemm_bt<DFF, D, 0, 1><<<dim3(DFF / 128, mr / 128), 256, 0, stream>>>(
          z + (size_t)m0 * D, w1_b + (size_t)l * DFF * D, b1 + l * DFF, nullptr, act, nullptr);
      if (l < 3)
        gemm_bt<D, DFF, 4, 0><<<dim3(D / 128, mr / 128), 256, 0, stream>>>(
            act, w2_b + (size_t)l * D * DFF, b2 + l * D, z + (size_t)m0 * D,
            z + (size_t)m0 * D, sacc + (size_t)m0 * 2);
      else
        gemm_bt<D, DFF, 1, 0><<<dim3(D / 128, mr / 128), 256, 0, stream>>>(
            act, w2_b + (size_t)l * D * DFF, b2 + l * D, z + (size_t)m0 * D,
            z + (size_t)m0 * D, nullptr);
    }
    if (l < 3) stats_fin<<<(M + 255) / 256, 256, 0, stream>>>(sacc, stats, M);
  }

  gemm_bt<OUTD, D, 2, 1><<<dim3(OUTD / 128, M / 128), 256, 0, stream>>>(
      z, wo_b, b_out, nullptr, out, nullptr);
}

// Round 12
// 3235.439 us; speedup vs baseline: 1.1153x; 1.0043x over previous
//
#include <hip/hip_runtime.h>
#include <hip/hip_bf16.h>
#include <cstdint>
#include <cstddef>

typedef __bf16 bf16;
typedef bf16 bf16x8 __attribute__((ext_vector_type(8)));
typedef bf16 bf16x4 __attribute__((ext_vector_type(4)));
typedef float f32x4 __attribute__((ext_vector_type(4)));
typedef unsigned int u32;

#define GLD_LDS16(gptr, lptr)                                                        \
  __builtin_amdgcn_global_load_lds((const __attribute__((address_space(1))) u32*)(gptr), \
                                   (__attribute__((address_space(3))) u32*)(lptr), 16, 0, 0)

// single-wave-block phase fence: LDS ops are in-order per wave, so a full barrier is
// overkill — wait LDS only, keep global loads (epilogue prefetch) in flight.
#define WAVE_FENCE()  do { asm volatile("s_waitcnt lgkmcnt(0)" ::: "memory"); \
                           __builtin_amdgcn_sched_barrier(0); } while (0)

static constexpr int S = 36, D = 768, H = 12, HD = 64, DFF = 1536;
static constexpr int BC = 1536;        // B*C images
static constexpr int M = BC * S;       // 55296 tokens
static constexpr int OUTD = 256;

// ---------------------------------------------------------------- fp32 -> bf16
__global__ __launch_bounds__(256) void f2b_kernel(const float* __restrict__ in,
                                                  bf16* __restrict__ out, int n4) {
  int i = blockIdx.x * 256 + threadIdx.x;
  if (i < n4) {
    float4 f = ((const float4*)in)[i];
    bf16x4 o = {(bf16)f.x, (bf16)f.y, (bf16)f.z, (bf16)f.w};
    ((bf16x4*)out)[i] = o;
  }
}

// ---------------------------------------------------------------- zero / stats finalize
__global__ __launch_bounds__(256) void zerok(float* __restrict__ p, int n) {
  int i = blockIdx.x * 256 + threadIdx.x;
  if (i < n) p[i] = 0.f;
}
// finalize (mean, rstd) and re-zero sacc for the next layer's accumulation
__global__ __launch_bounds__(256) void stats_fin(float* __restrict__ sacc,
                                                 float* __restrict__ stats, int n) {
  int i = blockIdx.x * 256 + threadIdx.x;
  if (i < n) {
    float sm = sacc[(size_t)i * 2] * (1.f / 768.f);
    float sq = sacc[(size_t)i * 2 + 1] * (1.f / 768.f);
    float var = sq - sm * sm;
    stats[(size_t)i * 2] = sm;
    stats[(size_t)i * 2 + 1] = rsqrtf(var + 1e-5f);
    sacc[(size_t)i * 2] = 0.f;
    sacc[(size_t)i * 2 + 1] = 0.f;
  }
}

// ---------------------------------------------------------------- Wqk = Wq^T Wk, vk = Wk^T bq
__global__ __launch_bounds__(64) void qk_prep(const float* __restrict__ Wq,
                                              const float* __restrict__ Wk,
                                              const float* __restrict__ bq,
                                              bf16* __restrict__ wb,
                                              float* __restrict__ vkout) {
  int lh = blockIdx.x;                 // 0..47 = l*12+h
  int e = threadIdx.x;                 // 0..63
  __shared__ float Wqs[64][64];        // [f][d]
  __shared__ float Wks[64][64];        // [f][e]
  const float* wqp = Wq + (size_t)lh * 4096;
  const float* wkp = Wk + (size_t)lh * 4096;
  for (int i = e; i < 4096; i += 64) {
    Wqs[i >> 6][i & 63] = wqp[i];
    Wks[i >> 6][i & 63] = wkp[i];
  }
  __syncthreads();
  float ks[64];
#pragma unroll
  for (int f = 0; f < 64; ++f) ks[f] = Wks[f][e];
  for (int d0 = 0; d0 < 64; d0 += 4) {
    float a0 = 0.f, a1 = 0.f, a2 = 0.f, a3 = 0.f;
#pragma unroll
    for (int f = 0; f < 64; ++f) {
      float4 wq4 = *(const float4*)&Wqs[f][d0];   // broadcast read
      a0 += wq4.x * ks[f]; a1 += wq4.y * ks[f];
      a2 += wq4.z * ks[f]; a3 += wq4.w * ks[f];
    }
    bf16x4 o = {(bf16)a0, (bf16)a1, (bf16)a2, (bf16)a3};
    *(bf16x4*)&wb[(size_t)lh * 4096 + e * 64 + d0] = o;
  }
  const float* bqp = bq + lh * 64;
  float acc = 0.f;
#pragma unroll
  for (int f = 0; f < 64; ++f) acc += ks[f] * bqp[f];
  vkout[lh * 64 + e] = acc;
}

// ---------------------------------------------------------------- patch embed
__global__ __launch_bounds__(256) void patch_embed(const float* __restrict__ batch,
                                                   const float* __restrict__ Wp,
                                                   const float* __restrict__ bp,
                                                   const float* __restrict__ pos,
                                                   float* __restrict__ z) {
  int bc = blockIdx.x, tid = threadIdx.x;
  __shared__ float p[36][40];          // [token][pixel], padded row
  for (int i = tid; i < 1296; i += 256) {
    float f = batch[(size_t)bc * 1296 + i];
    int row = i / 36, col = i - row * 36;
    p[(row / 6) * 6 + col / 6][(row % 6) * 6 + (col % 6)] = f;
  }
  __syncthreads();
  for (int c0 = 0; c0 < 768; c0 += 256) {
    int d = c0 + tid;
    float wr[36];
    const float4* wp4 = (const float4*)(Wp + (size_t)d * 36);   // 144B rows, 16B aligned
#pragma unroll
    for (int q = 0; q < 9; ++q) {
      float4 f = wp4[q];
      wr[q * 4] = f.x; wr[q * 4 + 1] = f.y; wr[q * 4 + 2] = f.z; wr[q * 4 + 3] = f.w;
    }
    float gb = bp[d];
    for (int s = 0; s < 36; ++s) {
      float acc = 0.f;
#pragma unroll
      for (int k = 0; k < 36; ++k) acc += p[s][k] * wr[k];
      z[((size_t)bc * 36 + s) * 768 + d] = acc + gb + pos[s * 768 + d];
    }
  }
}

// ---------------------------------------------------------------- LN stats (mean, rstd) per row
__global__ __launch_bounds__(256) void ln_stats(const float* __restrict__ zin,
                                                float* __restrict__ stats) {
  int row = blockIdx.x * 4 + (threadIdx.x >> 6);
  int lane = threadIdx.x & 63;
  const float* zr = zin + (size_t)row * D;
  float x[12];
#pragma unroll
  for (int i = 0; i < 12; ++i) x[i] = zr[i * 64 + lane];
  float s = 0.f;
#pragma unroll
  for (int i = 0; i < 12; ++i) s += x[i];
#pragma unroll
  for (int off = 32; off >= 1; off >>= 1) s += __shfl_xor(s, off, 64);
  float m = s * (1.f / 768.f);
  float v = 0.f;
#pragma unroll
  for (int i = 0; i < 12; ++i) { float dd = x[i] - m; v += dd * dd; }
#pragma unroll
  for (int off = 32; off >= 1; off >>= 1) v += __shfl_xor(v, off, 64);
  v *= (1.f / 768.f);
  if (lane == 0) {
    stats[(size_t)row * 2] = m;
    stats[(size_t)row * 2 + 1] = rsqrtf(v + 1e-5f);
  }
}

// ---------------------------------------------------------------- LN in-place (fp32)
__global__ __launch_bounds__(256) void ln_inplace(float* __restrict__ z,
                                                  const float* __restrict__ g,
                                                  const float* __restrict__ bt) {
  int row = blockIdx.x * 4 + (threadIdx.x >> 6);
  int lane = threadIdx.x & 63;
  float* zr = z + (size_t)row * D;
  float x[12];
#pragma unroll
  for (int i = 0; i < 12; ++i) x[i] = zr[i * 64 + lane];
  float s = 0.f;
#pragma unroll
  for (int i = 0; i < 12; ++i) s += x[i];
#pragma unroll
  for (int off = 32; off >= 1; off >>= 1) s += __shfl_xor(s, off, 64);
  float m = s * (1.f / 768.f);
  float v = 0.f;
#pragma unroll
  for (int i = 0; i < 12; ++i) { float dd = x[i] - m; v += dd * dd; }
#pragma unroll
  for (int off = 32; off >= 1; off >>= 1) v += __shfl_xor(v, off, 64);
  v *= (1.f / 768.f);
  float rstd = rsqrtf(v + 1e-5f);
#pragma unroll
  for (int i = 0; i < 12; ++i) {
    int d = i * 64 + lane;
    zr[d] = (x[i] - m) * rstd * g[d] + bt[d];
  }
}

// ---------------------------------------------------------------- fused attention (G-trick)
// R9 (latency-chain edition): single-wave block, so the 3 __syncthreads (each forcing
// a vmcnt(0) drain) are replaced by LDS-only fences; the epilogue z reads are
// prefetched right after the hfrag build (latency hides under 90 MFMAs); MFMA
// clusters run at setprio(1) so this wave's matrix ops preempt other blocks' loads.
__global__ __launch_bounds__(64) void attn_kernel(const float* __restrict__ zg,
                                                  const float* __restrict__ stats,
                                                  const float* __restrict__ g1,
                                                  const float* __restrict__ b1_,
                                                  const bf16* __restrict__ Wqk,
                                                  const bf16* __restrict__ Wv,
                                                  const float* __restrict__ vk,
                                                  const float* __restrict__ bv,
                                                  float* __restrict__ z) {
  int head = blockIdx.x;
  int bc = blockIdx.y;
  __shared__ __align__(16) bf16 gb[48 * 72];   // G, later P
  __shared__ __align__(16) bf16 vt[64 * 72];   // vt[e][t]
  int lane = threadIdx.x;
  int lr = lane & 15, quad = lane >> 4;

#pragma unroll
  for (int t0 = 0; t0 < 16; ++t0) vt[lane * 72 + 48 + t0] = (bf16)0.f;

  const float* zsrc = zg + ((size_t)bc * S) * D + head * HD;
  const float* st = stats + (size_t)bc * S * 2;

  float gv[2][8], bvv[2][8];
#pragma unroll
  for (int kt = 0; kt < 2; ++kt) {
    int c0 = head * HD + kt * 32 + quad * 8;
    float4 ga = *(const float4*)(g1 + c0);
    float4 gb2 = *(const float4*)(g1 + c0 + 4);
    float4 ba = *(const float4*)(b1_ + c0);
    float4 bb2 = *(const float4*)(b1_ + c0 + 4);
    gv[kt][0] = ga.x; gv[kt][1] = ga.y; gv[kt][2] = ga.z; gv[kt][3] = ga.w;
    gv[kt][4] = gb2.x; gv[kt][5] = gb2.y; gv[kt][6] = gb2.z; gv[kt][7] = gb2.w;
    bvv[kt][0] = ba.x; bvv[kt][1] = ba.y; bvv[kt][2] = ba.z; bvv[kt][3] = ba.w;
    bvv[kt][4] = bb2.x; bvv[kt][5] = bb2.y; bvv[kt][6] = bb2.z; bvv[kt][7] = bb2.w;
  }

  bf16x8 hfrag[3][2];
#pragma unroll
  for (int mt = 0; mt < 3; ++mt) {
    int srow = mt * 16 + lr;
    if (srow < 36) {
      float mm = st[srow * 2], rr = st[srow * 2 + 1];
#pragma unroll
      for (int kt = 0; kt < 2; ++kt) {
        int c0 = kt * 32 + quad * 8;
        float4 f0 = *(const float4*)(zsrc + (size_t)srow * D + c0);
        float4 f1 = *(const float4*)(zsrc + (size_t)srow * D + c0 + 4);
        float hv[8] = {f0.x, f0.y, f0.z, f0.w, f1.x, f1.y, f1.z, f1.w};
        bf16x8 o;
#pragma unroll
        for (int j = 0; j < 8; ++j) o[j] = (bf16)((hv[j] - mm) * rr * gv[kt][j] + bvv[kt][j]);
        hfrag[mt][kt] = o;
      }
    } else {
#pragma unroll
      for (int kt = 0; kt < 2; ++kt) {
        bf16x8 o;
#pragma unroll
        for (int j = 0; j < 8; ++j) o[j] = (bf16)0.f;
        hfrag[mt][kt] = o;
      }
    }
  }

  // epilogue z prefetch: issue the ~36 reads now; ~600cy latency hides under the
  // 90 MFMAs + softmax below. Values are stable (blocks write disjoint slices).
  float zv[3][4][4];
#pragma unroll
  for (int mt = 0; mt < 3; ++mt)
#pragma unroll
    for (int nt = 0; nt < 4; ++nt)
#pragma unroll
      for (int r = 0; r < 4; ++r) {
        int s2 = mt * 16 + quad * 4 + r;
        zv[mt][nt][r] = (s2 < 36) ? zsrc[(size_t)s2 * D + nt * 16 + lr] : 0.f;
      }

  float vkv[2][8];
#pragma unroll
  for (int kt = 0; kt < 2; ++kt) {
    int c0 = head * 64 + kt * 32 + quad * 8;
    float4 va = *(const float4*)(vk + c0);
    float4 vb2 = *(const float4*)(vk + c0 + 4);
    vkv[kt][0] = va.x; vkv[kt][1] = va.y; vkv[kt][2] = va.z; vkv[kt][3] = va.w;
    vkv[kt][4] = vb2.x; vkv[kt][5] = vb2.y; vkv[kt][6] = vb2.z; vkv[kt][7] = vb2.w;
  }
  float tv[3];
#pragma unroll
  for (int mt = 0; mt < 3; ++mt) {
    float sp = 0.f;
#pragma unroll
    for (int kt = 0; kt < 2; ++kt)
#pragma unroll
      for (int j = 0; j < 8; ++j) sp += (float)hfrag[mt][kt][j] * vkv[kt][j];
    sp += __shfl_xor(sp, 16, 64);
    sp += __shfl_xor(sp, 32, 64);
    tv[mt] = sp;
  }

  const bf16* Wm[2] = {Wqk + (size_t)head * 4096, Wv + (size_t)head * 4096};
  const float* bvp = bv + head * 64;
  for (int p = 0; p < 2; ++p) {
    bf16x8 bfr[4][2];
#pragma unroll
    for (int nt = 0; nt < 4; ++nt)
#pragma unroll
      for (int kt = 0; kt < 2; ++kt)
        bfr[nt][kt] = *(const bf16x8*)(Wm[p] + (nt * 16 + lr) * 64 + kt * 32 + quad * 8);
#pragma unroll
    for (int mt = 0; mt < 3; ++mt) {
      f32x4 acc[4] = {};
      __builtin_amdgcn_s_setprio(1);
#pragma unroll
      for (int kt = 0; kt < 2; ++kt)
#pragma unroll
        for (int nt = 0; nt < 4; ++nt)
          acc[nt] = __builtin_amdgcn_mfma_f32_16x16x32_bf16(hfrag[mt][kt], bfr[nt][kt], acc[nt], 0, 0, 0);
      __builtin_amdgcn_s_setprio(0);
#pragma unroll
      for (int nt = 0; nt < 4; ++nt) {
        float bb = (p == 1) ? bvp[nt * 16 + lr] : 0.f;
#pragma unroll
        for (int r = 0; r < 4; ++r) {
          int s2 = mt * 16 + quad * 4 + r;
          int e = nt * 16 + lr;
          float val = acc[nt][r] + bb;
          if (p == 0) gb[s2 * 72 + e] = (bf16)val;
          else vt[e * 72 + s2] = (bf16)val;
        }
      }
    }
  }
  WAVE_FENCE();                         // LDS writes visible to own-wave reads

  f32x4 sc[3][3];
#pragma unroll
  for (int mt = 0; mt < 3; ++mt)
#pragma unroll
    for (int nt = 0; nt < 3; ++nt) {
      f32x4 a = {};
      __builtin_amdgcn_s_setprio(1);
#pragma unroll
      for (int kt = 0; kt < 2; ++kt) {
        bf16x8 af = *(const bf16x8*)&gb[(mt * 16 + lr) * 72 + kt * 32 + quad * 8];
        a = __builtin_amdgcn_mfma_f32_16x16x32_bf16(af, hfrag[nt][kt], a, 0, 0, 0);
      }
      __builtin_amdgcn_s_setprio(0);
      int t = nt * 16 + lr;
#pragma unroll
      for (int r = 0; r < 4; ++r) {
        float v = (a[r] + tv[nt]) * 0.125f;     // 1/sqrt(64)
        if (t >= 36) v = -1e30f;
        sc[mt][nt][r] = v;
      }
    }
  WAVE_FENCE();                         // scores' gb reads done before P overwrites

#pragma unroll
  for (int mt = 0; mt < 3; ++mt) {
    float mx[4], sum[4];
#pragma unroll
    for (int r = 0; r < 4; ++r)
      mx[r] = fmaxf(fmaxf(sc[mt][0][r], sc[mt][1][r]), sc[mt][2][r]);
#pragma unroll
    for (int r = 0; r < 4; ++r)
#pragma unroll
      for (int off = 8; off >= 1; off >>= 1) mx[r] = fmaxf(mx[r], __shfl_xor(mx[r], off, 64));
#pragma unroll
    for (int r = 0; r < 4; ++r) sum[r] = 0.f;
#pragma unroll
    for (int nt = 0; nt < 3; ++nt)
#pragma unroll
      for (int r = 0; r < 4; ++r) {
        float e = __expf(sc[mt][nt][r] - mx[r]);
        sc[mt][nt][r] = e;
        sum[r] += e;
      }
#pragma unroll
    for (int r = 0; r < 4; ++r)
#pragma unroll
      for (int off = 8; off >= 1; off >>= 1) sum[r] += __shfl_xor(sum[r], off, 64);
#pragma unroll
    for (int nt = 0; nt < 4; ++nt)
#pragma unroll
      for (int r = 0; r < 4; ++r) {
        int s2 = mt * 16 + quad * 4 + r;
        int t = nt * 16 + lr;
        float pv = (nt < 3) ? sc[mt][nt][r] / sum[r] : 0.f;
        gb[s2 * 72 + t] = (bf16)pv;
      }
  }
  WAVE_FENCE();                         // P writes visible to own-wave PV reads

#pragma unroll
  for (int mt = 0; mt < 3; ++mt) {
    f32x4 o[4] = {};
    __builtin_amdgcn_s_setprio(1);
#pragma unroll
    for (int kt = 0; kt < 2; ++kt) {
      bf16x8 a = *(const bf16x8*)&gb[(mt * 16 + lr) * 72 + kt * 32 + quad * 8];
#pragma unroll
      for (int nt = 0; nt < 4; ++nt) {
        bf16x8 b = *(const bf16x8*)&vt[(nt * 16 + lr) * 72 + kt * 32 + quad * 8];
        o[nt] = __builtin_amdgcn_mfma_f32_16x16x32_bf16(a, b, o[nt], 0, 0, 0);
      }
    }
    __builtin_amdgcn_s_setprio(0);
#pragma unroll
    for (int nt = 0; nt < 4; ++nt)
#pragma unroll
      for (int r = 0; r < 4; ++r) {
        int s2 = mt * 16 + quad * 4 + r;
        if (s2 < 36) {
          int e = nt * 16 + lr;
          size_t idx = ((size_t)bc * S + s2) * D + head * HD + e;
          z[idx] = zv[mt][nt][r] + o[nt][r];    // prefetched read: pure store here
        }
      }
  }
}

// ---------------------------------------------------------------- GEMM (B^T layout)
// R7-verified two-barrier loop + XCD-aware bijective swizzle + MODE 4 fused LN1 stats.
// MODE 0: bf16 relu(.+bias); MODE 1: f32 .+bias+res; MODE 2: f32 .+bias;
// MODE 4: MODE1 + per-row sum/sumsq atomics. AF32 1: A fp32 via VGPR+convert.
template <int N, int K, int MODE, int AF32>
__global__ __launch_bounds__(256) void gemm_bt(const void* __restrict__ A,
                                               const bf16* __restrict__ Bw,
                                               const float* __restrict__ bias,
                                               const float* __restrict__ res,
                                               void* __restrict__ outp,
                                               float* __restrict__ sacc) {
  constexpr int BK = 64;
  __shared__ __align__(16) bf16 As[128 * BK];
  __shared__ __align__(16) bf16 Bs[128 * BK];
  int tid = threadIdx.x;
  int bn = blockIdx.x, bm = blockIdx.y;
  if ((gridDim.y & 7) == 0) {
    int gx = gridDim.x, gy = gridDim.y;
    int h = bm * gx + bn;
    int x = h & 7, k = h >> 3;
    int gpc = gy >> 3;                 // bm-groups per class
    bm = x * gpc + k / gx;
    bn = k - (k / gx) * gx;
  }
  const bf16* Abf = (const bf16*)A + (size_t)bm * 128 * K;
  const float* Af = (const float*)A + (size_t)bm * 128 * K;
  const bf16* Bb = Bw + (size_t)bn * 128 * K;
  int lane = tid & 63, wave = tid >> 6;
  int wm = (wave >> 1) * 64, wn = (wave & 1) * 64;
  int lr = lane & 15, quad = lane >> 4;
  f32x4 acc[4][4] = {};
  for (int k0 = 0; k0 < K; k0 += BK) {
    if (AF32) {
#pragma unroll
      for (int r = 0; r < 8; ++r) {
        int c = r * 256 + tid;            // 0..2047 float4-units
        int row = c >> 4, col4 = (c & 15) * 4;
        float4 f = *(const float4*)(Af + (size_t)row * K + k0 + col4);
        bf16x4 o = {(bf16)f.x, (bf16)f.y, (bf16)f.z, (bf16)f.w};
        *(bf16x4*)&As[row * BK + col4] = o;
      }
    } else {
#pragma unroll
      for (int r = 0; r < 4; ++r) {
        int c = r * 256 + tid;
        int row = c >> 3, col = (c & 7) * 8;
        GLD_LDS16(Abf + (size_t)row * K + k0 + col, &As[c * 8]);
      }
    }
#pragma unroll
    for (int r = 0; r < 4; ++r) {
      int c = r * 256 + tid;
      int row = c >> 3, col = (c & 7) * 8;
      GLD_LDS16(Bb + (size_t)row * K + k0 + col, &Bs[c * 8]);
    }
    __syncthreads();
#pragma unroll
    for (int kt = 0; kt < 2; ++kt) {
      bf16x8 af[4], bfr[4];
#pragma unroll
      for (int mt = 0; mt < 4; ++mt) af[mt] = *(const bf16x8*)&As[(wm + mt * 16 + lr) * BK + kt * 32 + quad * 8];
#pragma unroll
      for (int nt = 0; nt < 4; ++nt) bfr[nt] = *(const bf16x8*)&Bs[(wn + nt * 16 + lr) * BK + kt * 32 + quad * 8];
#pragma unroll
      for (int mt = 0; mt < 4; ++mt)
#pragma unroll
        for (int nt = 0; nt < 4; ++nt)
          acc[mt][nt] = __builtin_amdgcn_mfma_f32_16x16x32_bf16(af[mt], bfr[nt], acc[mt][nt], 0, 0, 0);
    }
    __syncthreads();
  }
  int row0 = bm * 128 + wm + quad * 4;
  int col0 = bn * 128 + wn + lr;
  if (MODE == 4) {
#pragma unroll
    for (int mt = 0; mt < 4; ++mt)
#pragma unroll
      for (int r = 0; r < 4; ++r) {
        int row = row0 + mt * 16 + r;
        float rs = 0.f, rq = 0.f;
#pragma unroll
        for (int nt = 0; nt < 4; ++nt) {
          int col = col0 + nt * 16;
          size_t idx = (size_t)row * N + col;
          float o = acc[mt][nt][r] + bias[col] + res[idx];
          ((float*)outp)[idx] = o;
          rs += o; rq += o * o;
        }
#pragma unroll
        for (int off = 8; off >= 1; off >>= 1) {
          rs += __shfl_xor(rs, off, 64);
          rq += __shfl_xor(rq, off, 64);
        }
        if (lr == 0) {
          atomicAdd(&sacc[(size_t)row * 2], rs);
          atomicAdd(&sacc[(size_t)row * 2 + 1], rq);
        }
      }
  } else {
#pragma unroll
    for (int mt = 0; mt < 4; ++mt)
#pragma unroll
      for (int nt = 0; nt < 4; ++nt) {
        int col = col0 + nt * 16;
        float bv = bias[col];
#pragma unroll
        for (int r = 0; r < 4; ++r) {
          size_t idx = (size_t)(row0 + mt * 16 + r) * N + col;
          float v = acc[mt][nt][r] + bv;
          if (MODE == 0) ((bf16*)outp)[idx] = (bf16)fmaxf(v, 0.f);
          else if (MODE == 1) ((float*)outp)[idx] = v + res[idx];
          else ((float*)outp)[idx] = v;
        }
      }
  }
}

// ---------------------------------------------------------------- launch
extern "C" void kernel_launch(void* const* d_in, const int* in_sizes, int n_in,
                              void* d_out, int out_size, void* d_ws, size_t ws_size,
                              hipStream_t stream) {
  const float* batch   = (const float*)d_in[0];
  const float* W_patch = (const float*)d_in[1];
  const float* b_patch = (const float*)d_in[2];
  const float* pos     = (const float*)d_in[3];
  const float* ln1_g   = (const float*)d_in[4];
  const float* ln1_b   = (const float*)d_in[5];
  const float* Wq      = (const float*)d_in[6];
  const float* bq      = (const float*)d_in[7];
  const float* Wk      = (const float*)d_in[8];
  const float* bk      = (const float*)d_in[9];
  const float* Wv      = (const float*)d_in[10];
  const float* bv      = (const float*)d_in[11];
  const float* ln2_g   = (const float*)d_in[12];
  const float* ln2_b   = (const float*)d_in[13];
  const float* W1      = (const float*)d_in[14];
  const float* b1      = (const float*)d_in[15];
  const float* W2      = (const float*)d_in[16];
  const float* b2      = (const float*)d_in[17];
  const float* W_out   = (const float*)d_in[18];
  const float* b_out   = (const float*)d_in[19];
  float* out = (float*)d_out;
  (void)bk;   // folded out: softmax-invariant terms

  char* ws = (char*)d_ws;
  size_t off = 0;
  float* z     = (float*)(ws + off); off += (size_t)M * D * 4;        // 169,869,312
  float* stats = (float*)(ws + off); off += (size_t)M * 2 * 4;
  float* sacc  = (float*)(ws + off); off += (size_t)M * 2 * 4;
  bf16* wqk_b = (bf16*)(ws + off);   off += (size_t)4 * H * 4096 * 2; // Wq^T Wk, bf16
  bf16* wv_b = (bf16*)(ws + off);    off += (size_t)4 * H * 4096 * 2;
  float* vk_f = (float*)(ws + off);  off += (size_t)4 * H * 64 * 4;   // Wk^T bq, f32
  bf16* w1_b = (bf16*)(ws + off);    off += (size_t)4 * DFF * D * 2;
  bf16* w2_b = (bf16*)(ws + off);    off += (size_t)4 * D * DFF * 2;
  bf16* wo_b = (bf16*)(ws + off);    off += (size_t)OUTD * D * 2;
  bf16* act  = (bf16*)(ws + off);    // remainder, chunked

  size_t avail = ws_size > off ? ws_size - off : (size_t)0;
  long long rcl = (long long)(avail / ((size_t)DFF * 2));
  int rc = (rcl > (long long)M) ? M : (int)rcl;
  rc = (rc / 1024) * 1024;             // x1024 keeps gridDim.y%8==0 -> swizzle active
  if (rc <= 0) rc = 128;

  qk_prep<<<48, 64, 0, stream>>>(Wq, Wk, bq, wqk_b, vk_f);
  f2b_kernel<<<192, 256, 0, stream>>>(Wv, wv_b, 49152);
  f2b_kernel<<<4608, 256, 0, stream>>>(W1, w1_b, 1179648);
  f2b_kernel<<<4608, 256, 0, stream>>>(W2, w2_b, 1179648);
  f2b_kernel<<<192, 256, 0, stream>>>(W_out, wo_b, 49152);

  patch_embed<<<BC, 256, 0, stream>>>(batch, W_patch, b_patch, pos, z);
  ln_stats<<<M / 4, 256, 0, stream>>>(z, stats);                       // LN1 stats, layer 0
  zerok<<<(M * 2 + 255) / 256, 256, 0, stream>>>(sacc, M * 2);         // once; stats_fin re-zeros

  for (int l = 0; l < 4; ++l) {
    attn_kernel<<<dim3(H, BC), 64, 0, stream>>>(z, stats, ln1_g + l * D, ln1_b + l * D,
        wqk_b + (size_t)l * H * 4096, wv_b + (size_t)l * H * 4096,
        vk_f + (size_t)l * H * 64, bv + (size_t)l * H * 64, z);
    ln_inplace<<<M / 4, 256, 0, stream>>>(z, ln2_g + l * D, ln2_b + l * D);
    for (int m0 = 0; m0 < M; m0 += rc) {
      int mr = (M - m0 < rc) ? (M - m0) : rc;
      gemm_bt<DFF, D, 0, 1><<<dim3(DFF / 128, mr / 128), 256, 0, stream>>>(
          z + (size_t)m0 * D, w1_b + (size_t)l * DFF * D, b1 + l * DFF, nullptr, act, nullptr);
      if (l < 3)
        gemm_bt<D, DFF, 4, 0><<<dim3(D / 128, mr / 128), 256, 0, stream>>>(
            act, w2_b + (size_t)l * D * DFF, b2 + l * D, z + (size_t)m0 * D,
            z + (size_t)m0 * D, sacc + (size_t)m0 * 2);
      else
        gemm_bt<D, DFF, 1, 0><<<dim3(D / 128, mr / 128), 256, 0, stream>>>(
            act, w2_b + (size_t)l * D * DFF, b2 + l * D, z + (size_t)m0 * D,
            z + (size_t)m0 * D, nullptr);
    }
    if (l < 3) stats_fin<<<(M + 255) / 256, 256, 0, stream>>>(sacc, stats, M);
  }

  gemm_bt<OUTD, D, 2, 1><<<dim3(OUTD / 128, M / 128), 256, 0, stream>>>(
      z, wo_b, b_out, nullptr, out, nullptr);
}